// Round 4
// baseline (256.751 us; speedup 1.0000x reference)
//
#include <hip/hip_runtime.h>

// LIF spiking recurrence over T=8:
//   mem = mem*TAU + x[t]*alpha; spike = (mem > Vth); mem = spike ? 0 : mem
// One thread per float4 (4 spatial positions).
//
// R12: DIAGNOSTIC. The LIF kernel has never appeared in the top-5 rocprof
// rows (it's faster than the ~80us poison fills), so every bandwidth/policy
// theory so far ran blind: R9-R11 (counted-vmcnt pipeline, cacheable stores)
// were all neutral at dur_us ~232-234. This round runs the identical
// best-known body (R8: asm nt loads, one vmcnt(0) drain, builtin nt stores)
// TWICE in one dispatch — LIF is a pure function of x, so pass 2 rewrites
// identical values (idempotent, race-free per-thread). The ~140us dispatch
// tops the profile and yields the kernel's own FETCH_SIZE / WRITE_SIZE /
// hbm_gbps / OccupancyPercent / VALUBusy. dur_us will regress to ~300 by
// design; the information selects the next branch:
//   FETCH≈WRITE≈262144 KB @ ~3.7 TB/s, occ high -> pattern wall confirmed
//   FETCH >> 262144 KB                          -> over-fetch, fix it
//   dur ~90-110us (2 passes < 2x71)             -> overhead-dominated, kernel
//                                                  already near roofline
//   occ low + hbm low                           -> latency-bound, raise TLP

#define TAU 0.5f
#define T_STEPS 8

typedef float vf4 __attribute__((ext_vector_type(4)));

__global__ __launch_bounds__(256) void lif_kernel(
    const float* __restrict__ x,
    const float* __restrict__ alpha_p,
    const float* __restrict__ vth_p,
    float* __restrict__ out,
    int n4)  // float4 groups per timestep
{
    const int i = blockIdx.x * blockDim.x + threadIdx.x;
    if (i >= n4) return;

    const float alpha = alpha_p[0];
    const float vth   = vth_p[0];

    const vf4* __restrict__ x4   = (const vf4*)x;
    vf4* __restrict__       out4 = (vf4*)out;

    const vf4* p0 = x4 + (size_t)0 * n4 + i;
    const vf4* p1 = x4 + (size_t)1 * n4 + i;
    const vf4* p2 = x4 + (size_t)2 * n4 + i;
    const vf4* p3 = x4 + (size_t)3 * n4 + i;
    const vf4* p4 = x4 + (size_t)4 * n4 + i;
    const vf4* p5 = x4 + (size_t)5 * n4 + i;
    const vf4* p6 = x4 + (size_t)6 * n4 + i;
    const vf4* p7 = x4 + (size_t)7 * n4 + i;

    // Two identical full passes. asm-volatile loads cannot be CSE'd, so
    // pass 2 re-reads x from HBM; stores rewrite identical values.
    for (int pass = 0; pass < 2; ++pass) {
        vf4 xt0, xt1, xt2, xt3, xt4, xt5, xt6, xt7;

        asm volatile("global_load_dwordx4 %0, %1, off nt" : "=v"(xt0) : "v"(p0));
        asm volatile("global_load_dwordx4 %0, %1, off nt" : "=v"(xt1) : "v"(p1));
        asm volatile("global_load_dwordx4 %0, %1, off nt" : "=v"(xt2) : "v"(p2));
        asm volatile("global_load_dwordx4 %0, %1, off nt" : "=v"(xt3) : "v"(p3));
        asm volatile("global_load_dwordx4 %0, %1, off nt" : "=v"(xt4) : "v"(p4));
        asm volatile("global_load_dwordx4 %0, %1, off nt" : "=v"(xt5) : "v"(p5));
        asm volatile("global_load_dwordx4 %0, %1, off nt" : "=v"(xt6) : "v"(p6));
        asm volatile("global_load_dwordx4 %0, %1, off nt" : "=v"(xt7) : "v"(p7));
        // Single drain; "+v" ties make every consumer depend on this asm.
        asm volatile("s_waitcnt vmcnt(0)"
                     : "+v"(xt0), "+v"(xt1), "+v"(xt2), "+v"(xt3),
                       "+v"(xt4), "+v"(xt5), "+v"(xt6), "+v"(xt7));

        vf4 mem = (vf4)(0.f);
        vf4 sp;

#define LIF_STEP(XT, T)                                   \
        do {                                              \
            mem = mem * TAU + (XT) * alpha;               \
            sp.x = (mem.x > vth) ? 1.f : 0.f;             \
            sp.y = (mem.y > vth) ? 1.f : 0.f;             \
            sp.z = (mem.z > vth) ? 1.f : 0.f;             \
            sp.w = (mem.w > vth) ? 1.f : 0.f;             \
            mem.x = (sp.x > 0.f) ? 0.f : mem.x;           \
            mem.y = (sp.y > 0.f) ? 0.f : mem.y;           \
            mem.z = (sp.z > 0.f) ? 0.f : mem.z;           \
            mem.w = (sp.w > 0.f) ? 0.f : mem.w;           \
            __builtin_nontemporal_store(                  \
                sp, &out4[(size_t)(T) * n4 + i]);         \
        } while (0)

        LIF_STEP(xt0, 0);
        LIF_STEP(xt1, 1);
        LIF_STEP(xt2, 2);
        LIF_STEP(xt3, 3);
        LIF_STEP(xt4, 4);
        LIF_STEP(xt5, 5);
        LIF_STEP(xt6, 6);
        LIF_STEP(xt7, 7);
#undef LIF_STEP
    }
}

extern "C" void kernel_launch(void* const* d_in, const int* in_sizes, int n_in,
                              void* d_out, int out_size, void* d_ws, size_t ws_size,
                              hipStream_t stream) {
    const float* x     = (const float*)d_in[0];
    const float* alpha = (const float*)d_in[1];
    const float* vth   = (const float*)d_in[2];
    float* out         = (float*)d_out;

    const int total = in_sizes[0];          // T * B * C * H * W
    const int n     = total / T_STEPS;      // spatial elements per timestep
    const int n4    = n / 4;                // float4 groups per timestep

    const int block = 256;
    const int grid  = (n4 + block - 1) / block;
    lif_kernel<<<grid, block, 0, stream>>>(x, alpha, vth, out, n4);
}

// Round 5
// 229.438 us; speedup vs baseline: 1.1190x; 1.1190x over previous
//
#include <hip/hip_runtime.h>

// LIF spiking recurrence over T=8:
//   mem = mem*TAU + x[t]*alpha; spike = (mem > Vth); mem = spike ? 0 : mem
//
// R13: spatial coarsening x4 — lengthen per-stream DRAM bursts.
// R12's counters (2-pass diagnostic): VALUBusy 3.9%, occupancy 61%,
// zero over-fetch, single-pass kernel ~63us = 4.3 TB/s vs 6.3 TB/s copy
// ceiling. Not latency-bound (~160KB outstanding/CU >> BW*latency), not
// policy-bound (R9-R11 neutral). Remaining variable: stream fragmentation —
// 8 read + 8 write streams at 16MiB stride with only 1KB per wave per
// stream; fills (1 stream) hit 6.65 TB/s, 1+1-stream copy 6.29 TB/s.
// Fix: each thread handles 4 wave-interleaved float4s so each WAVE moves
// 4KB contiguous per plane per direction (4 back-to-back coalesced 1KB
// instructions), loads and stores both grouped by plane. Same traffic,
// same nt-everything policy. All builtins (compiler owns store-data
// hazards — R9 failure mode).
// Predict: kernel 63 -> ~48-55us, dur_us 232 -> ~218-225. Neutral =>
// 16-stream mixed R/W DRAM pattern is at its efficiency roofline.

#define TAU 0.5f
#define T_STEPS 8
#define VW 4  // float4 groups per thread (spatial coarsening factor)

typedef float vf4 __attribute__((ext_vector_type(4)));

__global__ __launch_bounds__(256) void lif_kernel(
    const float* __restrict__ x,
    const float* __restrict__ alpha_p,
    const float* __restrict__ vth_p,
    float* __restrict__ out,
    int n4)  // float4 groups per timestep
{
    const int lane = threadIdx.x & 63;
    const int wave = threadIdx.x >> 6;
    // Wave owns VW*64 consecutive float4s per plane; block owns 4 waves'
    // worth. Lane layout keeps every load/store instruction coalesced
    // (lanes contiguous), and the VW instructions per plane are adjacent
    // 1KB chunks -> 4KB contiguous burst per wave per plane.
    const int base = blockIdx.x * (256 * VW) + wave * (64 * VW) + lane;

    const float alpha = alpha_p[0];
    const float vth   = vth_p[0];

    const vf4* __restrict__ x4   = (const vf4*)x;
    vf4* __restrict__       out4 = (vf4*)out;

    int  e[VW];
    bool ok[VW];
#pragma unroll
    for (int w = 0; w < VW; ++w) {
        e[w]  = base + w * 64;
        ok[w] = (e[w] < n4);
    }

    // All 32 nt loads issued up front, grouped by plane (t-major) so the
    // 4 chunks of each plane go out back-to-back.
    vf4 xt[T_STEPS][VW];
#pragma unroll
    for (int t = 0; t < T_STEPS; ++t) {
#pragma unroll
        for (int w = 0; w < VW; ++w) {
            if (ok[w])
                xt[t][w] = __builtin_nontemporal_load(
                    x4 + (size_t)t * n4 + e[w]);
        }
    }

    vf4 mem[VW];
#pragma unroll
    for (int w = 0; w < VW; ++w) mem[w] = (vf4)(0.f);

    // t-major compute/store: consumes xt in load order (smooth waitcnt
    // staging) and emits stores grouped by plane (4KB write bursts).
#pragma unroll
    for (int t = 0; t < T_STEPS; ++t) {
#pragma unroll
        for (int w = 0; w < VW; ++w) {
            if (!ok[w]) continue;
            vf4 m = mem[w] * TAU + xt[t][w] * alpha;
            vf4 sp;
            sp.x = (m.x > vth) ? 1.f : 0.f;
            sp.y = (m.y > vth) ? 1.f : 0.f;
            sp.z = (m.z > vth) ? 1.f : 0.f;
            sp.w = (m.w > vth) ? 1.f : 0.f;
            m.x = (sp.x > 0.f) ? 0.f : m.x;
            m.y = (sp.y > 0.f) ? 0.f : m.y;
            m.z = (sp.z > 0.f) ? 0.f : m.z;
            m.w = (sp.w > 0.f) ? 0.f : m.w;
            mem[w] = m;
            __builtin_nontemporal_store(
                sp, out4 + (size_t)t * n4 + e[w]);
        }
    }
}

extern "C" void kernel_launch(void* const* d_in, const int* in_sizes, int n_in,
                              void* d_out, int out_size, void* d_ws, size_t ws_size,
                              hipStream_t stream) {
    const float* x     = (const float*)d_in[0];
    const float* alpha = (const float*)d_in[1];
    const float* vth   = (const float*)d_in[2];
    float* out         = (float*)d_out;

    const int total = in_sizes[0];          // T * B * C * H * W
    const int n     = total / T_STEPS;      // spatial elements per timestep
    const int n4    = n / 4;                // float4 groups per timestep

    const int block = 256;
    const int per_block = block * VW;       // float4s per block per plane
    const int grid  = (n4 + per_block - 1) / per_block;
    lif_kernel<<<grid, block, 0, stream>>>(x, alpha, vth, out, n4);
}